// Round 6
// baseline (454.764 us; speedup 1.0000x reference)
//
#include <hip/hip_runtime.h>

#define BB 128
#define TT 2048
#define II 32
#define HH 64

// ws layout: float xh[2][BB][HH][TT]   (xw written by proj, overwritten in-place by h in rnn)
// total = 2*128*64*2048*4 = 128 MiB

__global__ __launch_bounds__(256) void proj_kernel(
    const float* __restrict__ x,
    const float* __restrict__ Wf, const float* __restrict__ bihf, const float* __restrict__ bhhf,
    const float* __restrict__ Wb, const float* __restrict__ bihb, const float* __restrict__ bhhb,
    float* __restrict__ xh)
{
    const int lane = threadIdx.x & 63;
    const int wv = __builtin_amdgcn_readfirstlane(threadIdx.x >> 6);
    const int blk = blockIdx.x;          // 0..4095
    const int b = blk >> 5;
    const int t = ((blk & 31) << 6) + lane;

    float xr[II];
    {
        const float4* xp = (const float4*)(x + ((size_t)b * TT + t) * II);
        #pragma unroll
        for (int k4 = 0; k4 < II / 4; ++k4) {
            float4 v = xp[k4];
            xr[4*k4+0] = v.x; xr[4*k4+1] = v.y; xr[4*k4+2] = v.z; xr[4*k4+3] = v.w;
        }
    }
    float* outF = xh + (size_t)b * HH * TT + t;
    float* outB = xh + (size_t)(BB + b) * HH * TT + t;
    #pragma unroll 4
    for (int ii = 0; ii < 16; ++ii) {
        const int i = wv * 16 + ii;                    // wave-uniform -> scalar W loads
        const float* wfr = Wf + i * II;
        const float* wbr = Wb + i * II;
        float af0 = bihf[i] + bhhf[i], af1 = 0.f;
        float ab0 = bihb[i] + bhhb[i], ab1 = 0.f;
        #pragma unroll
        for (int k = 0; k < II; k += 2) {
            af0 = fmaf(wfr[k],   xr[k],   af0);
            af1 = fmaf(wfr[k+1], xr[k+1], af1);
            ab0 = fmaf(wbr[k],   xr[k],   ab0);
            ab1 = fmaf(wbr[k+1], xr[k+1], ab1);
        }
        outF[(size_t)i * TT] = af0 + af1;   // coalesced 256B store
        outB[(size_t)i * TT] = ab0 + ab1;
    }
}

// ---------------- general-W fallback (serial chain), R2-proven ----------------
#define RNN_STEP(XOV, HQ, CURBUF, NXTBUF) {                                   \
    float a0 = (XOV), a1 = 0.f, a2 = 0.f, a3 = 0.f;                           \
    const float* hs = hsh[CURBUF];                                            \
    _Pragma("unroll")                                                         \
    for (int j4 = 0; j4 < HH / 4; ++j4) {                                     \
        float4 h4 = *(const float4*)(hs + 4 * j4);  /* ds_read_b128 bcast */  \
        a0 = fmaf(w[4*j4+0], h4.x, a0);                                       \
        a1 = fmaf(w[4*j4+1], h4.y, a1);                                       \
        a2 = fmaf(w[4*j4+2], h4.z, a2);                                       \
        a3 = fmaf(w[4*j4+3], h4.w, a3);                                       \
    }                                                                         \
    HQ = fmaxf((a0 + a1) + (a2 + a3), 0.0f);                                  \
    hsh[NXTBUF][lane] = HQ;                                                   \
}

template<int DIR>
__device__ __noinline__ void rnn_serial(const float* __restrict__ W,
                                        float* __restrict__ xh,
                                        int b, int lane)
{
    float w[HH];
    {
        const float4* wp = (const float4*)(W + lane * HH);
        #pragma unroll
        for (int j4 = 0; j4 < HH / 4; ++j4) {
            float4 v = wp[j4];
            w[4*j4+0] = v.x; w[4*j4+1] = v.y; w[4*j4+2] = v.z; w[4*j4+3] = v.w;
        }
    }
    float* base = xh + ((size_t)(DIR * BB + b) * HH + lane) * TT;

    __shared__ __align__(16) float hsh[2][HH];
    hsh[0][lane] = 0.0f;
    __syncthreads();

    constexpr int STEP = DIR ? -4 : 4;
    int gbase = DIR ? (TT - 4) : 0;
    float4 xq = *(const float4*)(base + gbase);

    for (int g = 0; g < TT / 4; ++g) {
        const int gnext = (g + 1 < TT / 4) ? (gbase + STEP) : gbase;
        const float4 xn = *(const float4*)(base + gnext);

        float hq0, hq1, hq2, hq3;
        if (DIR == 0) {
            RNN_STEP(xq.x, hq0, 0, 1)
            RNN_STEP(xq.y, hq1, 1, 0)
            RNN_STEP(xq.z, hq2, 0, 1)
            RNN_STEP(xq.w, hq3, 1, 0)
        } else {
            RNN_STEP(xq.w, hq0, 0, 1)
            RNN_STEP(xq.z, hq1, 1, 0)
            RNN_STEP(xq.y, hq2, 0, 1)
            RNN_STEP(xq.x, hq3, 1, 0)
        }

        float4 st;
        if (DIR == 0) { st.x = hq0; st.y = hq1; st.z = hq2; st.w = hq3; }
        else          { st.x = hq3; st.y = hq2; st.z = hq1; st.w = hq0; }
        *(float4*)(base + gbase) = st;

        gbase = gnext;
        xq = xn;
    }
}

// ---------------- rnn: identity fast-path (parallel scan) + fallback ----------
__global__ __launch_bounds__(64) void rnn_kernel(
    const float* __restrict__ Whf, const float* __restrict__ Whb,
    float* __restrict__ xh)
{
    const int lane = threadIdx.x;
    const int row  = blockIdx.x;         // 0..16383
    const int dir  = row >> 13;
    const int rid  = row & 8191;
    const int b    = rid >> 6;
    const int hrow = rid & 63;
    const float* W = dir ? Whb : Whf;

    bool ok = true;
    {
        const float4* wp = (const float4*)(W + lane * HH);
        #pragma unroll
        for (int j4 = 0; j4 < HH / 4; ++j4) {
            float4 v = wp[j4];
            ok &= (v.x == ((4*j4+0 == lane) ? 1.0f : 0.0f));
            ok &= (v.y == ((4*j4+1 == lane) ? 1.0f : 0.0f));
            ok &= (v.z == ((4*j4+2 == lane) ? 1.0f : 0.0f));
            ok &= (v.w == ((4*j4+3 == lane) ? 1.0f : 0.0f));
        }
    }
    const bool isI = (__ballot(ok) == ~0ull);

    if (!isI) {
        if (hrow != 0) return;
        if (dir == 0) rnn_serial<0>(Whf, xh, b, lane);
        else          rnn_serial<1>(Whb, xh, b, lane);
        return;
    }

    float* base = xh + ((size_t)(dir * BB + b) * HH + hrow) * TT;

    float a[32];
    if (dir == 0) {
        const float4* xp = (const float4*)(base + lane * 32);
        #pragma unroll
        for (int q = 0; q < 8; ++q) {
            float4 v = xp[q];
            a[4*q+0] = v.x; a[4*q+1] = v.y; a[4*q+2] = v.z; a[4*q+3] = v.w;
        }
    } else {
        const float4* xp = (const float4*)(base + (TT - 32 - lane * 32));
        #pragma unroll
        for (int q = 0; q < 8; ++q) {
            float4 v = xp[q];
            a[31-4*q] = v.x; a[30-4*q] = v.y; a[29-4*q] = v.z; a[28-4*q] = v.w;
        }
    }

    float A = 0.0f, Bv = -__builtin_inff();
    #pragma unroll
    for (int j = 0; j < 32; ++j) {
        A  = A + a[j];
        Bv = fmaxf(Bv + a[j], 0.0f);
    }

    #pragma unroll
    for (int off = 1; off < 64; off <<= 1) {
        float Au = __shfl_up(A,  (unsigned)off);
        float Bu = __shfl_up(Bv, (unsigned)off);
        if (lane >= off) {
            Bv = fmaxf(Bu + A, Bv);
            A  = Au + A;
        }
    }

    float Ae = __shfl_up(A, 1u);
    float Be = __shfl_up(Bv, 1u);
    float h = (lane == 0) ? 0.0f : fmaxf(Ae, Be);

    #pragma unroll
    for (int j = 0; j < 32; ++j) {
        h = fmaxf(h + a[j], 0.0f);
        a[j] = h;
    }

    if (dir == 0) {
        float4* op = (float4*)(base + lane * 32);
        #pragma unroll
        for (int q = 0; q < 8; ++q) {
            float4 st; st.x = a[4*q+0]; st.y = a[4*q+1]; st.z = a[4*q+2]; st.w = a[4*q+3];
            op[q] = st;
        }
    } else {
        float4* op = (float4*)(base + (TT - 32 - lane * 32));
        #pragma unroll
        for (int q = 0; q < 8; ++q) {
            float4 st; st.x = a[31-4*q]; st.y = a[30-4*q]; st.z = a[29-4*q]; st.w = a[28-4*q];
            op[q] = st;
        }
    }
}

// ---------------- mlp: register-resident h (128 NAMED scalars) ---------------
// R5 post-mortem: k-tiled streaming re-fetched xh ~8x from HBM (FETCH 518 MB,
// hbm-bound at 2.7 TB/s, VALUBusy 37%). Fix: load all 128 h once into NAMED
// scalars (no indexed array -> no SROA/scratch trap of R3/R4), then run the
// 8 k-tiles against register-resident h. w0 rows are wave-uniform s_loads.
#define REP16(M) M(0) M(1) M(2) M(3) M(4) M(5) M(6) M(7) \
                 M(8) M(9) M(10) M(11) M(12) M(13) M(14) M(15)
#define REP64(M) \
  M(0) M(1) M(2) M(3) M(4) M(5) M(6) M(7) M(8) M(9) M(10) M(11) M(12) M(13) M(14) M(15) \
  M(16) M(17) M(18) M(19) M(20) M(21) M(22) M(23) M(24) M(25) M(26) M(27) M(28) M(29) M(30) M(31) \
  M(32) M(33) M(34) M(35) M(36) M(37) M(38) M(39) M(40) M(41) M(42) M(43) M(44) M(45) M(46) M(47) \
  M(48) M(49) M(50) M(51) M(52) M(53) M(54) M(55) M(56) M(57) M(58) M(59) M(60) M(61) M(62) M(63)

#define WF4(i, OFF, A, B, C, D) { \
    float4 wq = *(const float4*)(wk + (OFF) + (i) * 128); \
    c##i = fmaf(wq.x, A, c##i); c##i = fmaf(wq.y, B, c##i); \
    c##i = fmaf(wq.z, C, c##i); c##i = fmaf(wq.w, D, c##i); }

#define CHUNK(OFF, A, B, C, D) \
    WF4(0,OFF,A,B,C,D)  WF4(1,OFF,A,B,C,D)  WF4(2,OFF,A,B,C,D)  WF4(3,OFF,A,B,C,D)  \
    WF4(4,OFF,A,B,C,D)  WF4(5,OFF,A,B,C,D)  WF4(6,OFF,A,B,C,D)  WF4(7,OFF,A,B,C,D)  \
    WF4(8,OFF,A,B,C,D)  WF4(9,OFF,A,B,C,D)  WF4(10,OFF,A,B,C,D) WF4(11,OFF,A,B,C,D) \
    WF4(12,OFF,A,B,C,D) WF4(13,OFF,A,B,C,D) WF4(14,OFF,A,B,C,D) WF4(15,OFF,A,B,C,D)

__global__ __launch_bounds__(256, 2) void mlp_kernel(
    const float* __restrict__ xh,
    const float* __restrict__ w0, const float* __restrict__ b0,
    const float* __restrict__ w1, const float* __restrict__ b1,
    float* __restrict__ out)
{
    const int lane = threadIdx.x & 63;
    const int tile = __builtin_amdgcn_readfirstlane(blockIdx.x * 4 + (threadIdx.x >> 6));
    const int b = tile >> 5;
    const int t = ((tile & 31) << 6) + lane;

    const float* pf = xh + (size_t)b * HH * TT + t;        // forward h, stride TT per j
    const float* pb = xh + (size_t)(BB + b) * HH * TT + t; // backward h

    // all 128 h values -> named scalars (one coalesced 256B load each)
    #define LHF(j) const float hf##j = pf[(size_t)(j) * TT];
    #define LHB(j) const float hb##j = pb[(size_t)(j) * TT];
    REP64(LHF)
    REP64(LHB)
    #undef LHF
    #undef LHB

    float oa = 0.0f;

    #pragma unroll 1
    for (int kt = 0; kt < 8; ++kt) {
        const float* wk = w0 + kt * 16 * 128;   // rows k = kt*16 .. kt*16+15

        #define DC(i) float c##i = b0[kt * 16 + i];
        REP16(DC)
        #undef DC

        // forward half: j = 0..63
        CHUNK(0,  hf0,hf1,hf2,hf3)    CHUNK(4,  hf4,hf5,hf6,hf7)
        CHUNK(8,  hf8,hf9,hf10,hf11)  CHUNK(12, hf12,hf13,hf14,hf15)
        CHUNK(16, hf16,hf17,hf18,hf19) CHUNK(20, hf20,hf21,hf22,hf23)
        CHUNK(24, hf24,hf25,hf26,hf27) CHUNK(28, hf28,hf29,hf30,hf31)
        CHUNK(32, hf32,hf33,hf34,hf35) CHUNK(36, hf36,hf37,hf38,hf39)
        CHUNK(40, hf40,hf41,hf42,hf43) CHUNK(44, hf44,hf45,hf46,hf47)
        CHUNK(48, hf48,hf49,hf50,hf51) CHUNK(52, hf52,hf53,hf54,hf55)
        CHUNK(56, hf56,hf57,hf58,hf59) CHUNK(60, hf60,hf61,hf62,hf63)
        // backward half: j = 64..127
        CHUNK(64, hb0,hb1,hb2,hb3)    CHUNK(68, hb4,hb5,hb6,hb7)
        CHUNK(72, hb8,hb9,hb10,hb11)  CHUNK(76, hb12,hb13,hb14,hb15)
        CHUNK(80, hb16,hb17,hb18,hb19) CHUNK(84, hb20,hb21,hb22,hb23)
        CHUNK(88, hb24,hb25,hb26,hb27) CHUNK(92, hb28,hb29,hb30,hb31)
        CHUNK(96, hb32,hb33,hb34,hb35) CHUNK(100,hb36,hb37,hb38,hb39)
        CHUNK(104,hb40,hb41,hb42,hb43) CHUNK(108,hb44,hb45,hb46,hb47)
        CHUNK(112,hb48,hb49,hb50,hb51) CHUNK(116,hb52,hb53,hb54,hb55)
        CHUNK(120,hb56,hb57,hb58,hb59) CHUNK(124,hb60,hb61,hb62,hb63)

        // leaky_relu + second layer, k order preserved
        #define EP(i) { float v = fmaxf(c##i, 0.01f * c##i); \
                        oa = fmaf(v, w1[kt * 16 + i], oa); }
        REP16(EP)
        #undef EP
    }

    out[(size_t)b * TT + t] = oa + b1[0];
}

extern "C" void kernel_launch(void* const* d_in, const int* in_sizes, int n_in,
                              void* d_out, int out_size, void* d_ws, size_t ws_size,
                              hipStream_t stream) {
    (void)in_sizes; (void)n_in; (void)out_size; (void)ws_size;
    const float* x    = (const float*)d_in[0];
    const float* Wihf = (const float*)d_in[1];
    const float* Whhf = (const float*)d_in[2];
    const float* bihf = (const float*)d_in[3];
    const float* bhhf = (const float*)d_in[4];
    const float* Wihb = (const float*)d_in[5];
    const float* Whhb = (const float*)d_in[6];
    const float* bihb = (const float*)d_in[7];
    const float* bhhb = (const float*)d_in[8];
    const float* ff0w = (const float*)d_in[9];
    const float* ff0b = (const float*)d_in[10];
    const float* ff1w = (const float*)d_in[11];
    const float* ff1b = (const float*)d_in[12];
    float* xh = (float*)d_ws;

    proj_kernel<<<dim3(BB * (TT / 64)), dim3(256), 0, stream>>>(
        x, Wihf, bihf, bhhf, Wihb, bihb, bhhb, xh);
    rnn_kernel<<<dim3(2 * BB * HH), dim3(64), 0, stream>>>(Whhf, Whhb, xh);
    mlp_kernel<<<dim3(BB * (TT / 64) / 4), dim3(256), 0, stream>>>(
        xh, ff0w, ff0b, ff1w, ff1b, (float*)d_out);
}

// Round 7
// 377.505 us; speedup vs baseline: 1.2047x; 1.2047x over previous
//
#include <hip/hip_runtime.h>

#define BB 128
#define TT 2048
#define II 32
#define HH 64

// ws layout: float xh[2][BB][HH][TT]   (xw written by proj, overwritten in-place by h in rnn)
// total = 2*128*64*2048*4 = 128 MiB

__global__ __launch_bounds__(256) void proj_kernel(
    const float* __restrict__ x,
    const float* __restrict__ Wf, const float* __restrict__ bihf, const float* __restrict__ bhhf,
    const float* __restrict__ Wb, const float* __restrict__ bihb, const float* __restrict__ bhhb,
    float* __restrict__ xh)
{
    const int lane = threadIdx.x & 63;
    const int wv = __builtin_amdgcn_readfirstlane(threadIdx.x >> 6);
    const int blk = blockIdx.x;          // 0..4095
    const int b = blk >> 5;
    const int t = ((blk & 31) << 6) + lane;

    float xr[II];
    {
        const float4* xp = (const float4*)(x + ((size_t)b * TT + t) * II);
        #pragma unroll
        for (int k4 = 0; k4 < II / 4; ++k4) {
            float4 v = xp[k4];
            xr[4*k4+0] = v.x; xr[4*k4+1] = v.y; xr[4*k4+2] = v.z; xr[4*k4+3] = v.w;
        }
    }
    float* outF = xh + (size_t)b * HH * TT + t;
    float* outB = xh + (size_t)(BB + b) * HH * TT + t;
    #pragma unroll 4
    for (int ii = 0; ii < 16; ++ii) {
        const int i = wv * 16 + ii;                    // wave-uniform -> scalar W loads
        const float* wfr = Wf + i * II;
        const float* wbr = Wb + i * II;
        float af0 = bihf[i] + bhhf[i], af1 = 0.f;
        float ab0 = bihb[i] + bhhb[i], ab1 = 0.f;
        #pragma unroll
        for (int k = 0; k < II; k += 2) {
            af0 = fmaf(wfr[k],   xr[k],   af0);
            af1 = fmaf(wfr[k+1], xr[k+1], af1);
            ab0 = fmaf(wbr[k],   xr[k],   ab0);
            ab1 = fmaf(wbr[k+1], xr[k+1], ab1);
        }
        outF[(size_t)i * TT] = af0 + af1;   // coalesced 256B store
        outB[(size_t)i * TT] = ab0 + ab1;
    }
}

// ---------------- general-W fallback (serial chain), R2-proven ----------------
#define RNN_STEP(XOV, HQ, CURBUF, NXTBUF) {                                   \
    float a0 = (XOV), a1 = 0.f, a2 = 0.f, a3 = 0.f;                           \
    const float* hs = hsh[CURBUF];                                            \
    _Pragma("unroll")                                                         \
    for (int j4 = 0; j4 < HH / 4; ++j4) {                                     \
        float4 h4 = *(const float4*)(hs + 4 * j4);  /* ds_read_b128 bcast */  \
        a0 = fmaf(w[4*j4+0], h4.x, a0);                                       \
        a1 = fmaf(w[4*j4+1], h4.y, a1);                                       \
        a2 = fmaf(w[4*j4+2], h4.z, a2);                                       \
        a3 = fmaf(w[4*j4+3], h4.w, a3);                                       \
    }                                                                         \
    HQ = fmaxf((a0 + a1) + (a2 + a3), 0.0f);                                  \
    hsh[NXTBUF][lane] = HQ;                                                   \
}

template<int DIR>
__device__ __noinline__ void rnn_serial(const float* __restrict__ W,
                                        float* __restrict__ xh,
                                        int b, int lane)
{
    float w[HH];
    {
        const float4* wp = (const float4*)(W + lane * HH);
        #pragma unroll
        for (int j4 = 0; j4 < HH / 4; ++j4) {
            float4 v = wp[j4];
            w[4*j4+0] = v.x; w[4*j4+1] = v.y; w[4*j4+2] = v.z; w[4*j4+3] = v.w;
        }
    }
    float* base = xh + ((size_t)(DIR * BB + b) * HH + lane) * TT;

    __shared__ __align__(16) float hsh[2][HH];
    hsh[0][lane] = 0.0f;
    __syncthreads();

    constexpr int STEP = DIR ? -4 : 4;
    int gbase = DIR ? (TT - 4) : 0;
    float4 xq = *(const float4*)(base + gbase);

    for (int g = 0; g < TT / 4; ++g) {
        const int gnext = (g + 1 < TT / 4) ? (gbase + STEP) : gbase;
        const float4 xn = *(const float4*)(base + gnext);

        float hq0, hq1, hq2, hq3;
        if (DIR == 0) {
            RNN_STEP(xq.x, hq0, 0, 1)
            RNN_STEP(xq.y, hq1, 1, 0)
            RNN_STEP(xq.z, hq2, 0, 1)
            RNN_STEP(xq.w, hq3, 1, 0)
        } else {
            RNN_STEP(xq.w, hq0, 0, 1)
            RNN_STEP(xq.z, hq1, 1, 0)
            RNN_STEP(xq.y, hq2, 0, 1)
            RNN_STEP(xq.x, hq3, 1, 0)
        }

        float4 st;
        if (DIR == 0) { st.x = hq0; st.y = hq1; st.z = hq2; st.w = hq3; }
        else          { st.x = hq3; st.y = hq2; st.z = hq1; st.w = hq0; }
        *(float4*)(base + gbase) = st;

        gbase = gnext;
        xq = xn;
    }
}

// ---------------- rnn: identity fast-path (parallel scan) + fallback ----------
__global__ __launch_bounds__(64) void rnn_kernel(
    const float* __restrict__ Whf, const float* __restrict__ Whb,
    float* __restrict__ xh)
{
    const int lane = threadIdx.x;
    const int row  = blockIdx.x;         // 0..16383
    const int dir  = row >> 13;
    const int rid  = row & 8191;
    const int b    = rid >> 6;
    const int hrow = rid & 63;
    const float* W = dir ? Whb : Whf;

    bool ok = true;
    {
        const float4* wp = (const float4*)(W + lane * HH);
        #pragma unroll
        for (int j4 = 0; j4 < HH / 4; ++j4) {
            float4 v = wp[j4];
            ok &= (v.x == ((4*j4+0 == lane) ? 1.0f : 0.0f));
            ok &= (v.y == ((4*j4+1 == lane) ? 1.0f : 0.0f));
            ok &= (v.z == ((4*j4+2 == lane) ? 1.0f : 0.0f));
            ok &= (v.w == ((4*j4+3 == lane) ? 1.0f : 0.0f));
        }
    }
    const bool isI = (__ballot(ok) == ~0ull);

    if (!isI) {
        if (hrow != 0) return;
        if (dir == 0) rnn_serial<0>(Whf, xh, b, lane);
        else          rnn_serial<1>(Whb, xh, b, lane);
        return;
    }

    float* base = xh + ((size_t)(dir * BB + b) * HH + hrow) * TT;

    float a[32];
    if (dir == 0) {
        const float4* xp = (const float4*)(base + lane * 32);
        #pragma unroll
        for (int q = 0; q < 8; ++q) {
            float4 v = xp[q];
            a[4*q+0] = v.x; a[4*q+1] = v.y; a[4*q+2] = v.z; a[4*q+3] = v.w;
        }
    } else {
        const float4* xp = (const float4*)(base + (TT - 32 - lane * 32));
        #pragma unroll
        for (int q = 0; q < 8; ++q) {
            float4 v = xp[q];
            a[31-4*q] = v.x; a[30-4*q] = v.y; a[29-4*q] = v.z; a[28-4*q] = v.w;
        }
    }

    float A = 0.0f, Bv = -__builtin_inff();
    #pragma unroll
    for (int j = 0; j < 32; ++j) {
        A  = A + a[j];
        Bv = fmaxf(Bv + a[j], 0.0f);
    }

    #pragma unroll
    for (int off = 1; off < 64; off <<= 1) {
        float Au = __shfl_up(A,  (unsigned)off);
        float Bu = __shfl_up(Bv, (unsigned)off);
        if (lane >= off) {
            Bv = fmaxf(Bu + A, Bv);
            A  = Au + A;
        }
    }

    float Ae = __shfl_up(A, 1u);
    float Be = __shfl_up(Bv, 1u);
    float h = (lane == 0) ? 0.0f : fmaxf(Ae, Be);

    #pragma unroll
    for (int j = 0; j < 32; ++j) {
        h = fmaxf(h + a[j], 0.0f);
        a[j] = h;
    }

    if (dir == 0) {
        float4* op = (float4*)(base + lane * 32);
        #pragma unroll
        for (int q = 0; q < 8; ++q) {
            float4 st; st.x = a[4*q+0]; st.y = a[4*q+1]; st.z = a[4*q+2]; st.w = a[4*q+3];
            op[q] = st;
        }
    } else {
        float4* op = (float4*)(base + (TT - 32 - lane * 32));
        #pragma unroll
        for (int q = 0; q < 8; ++q) {
            float4 st; st.x = a[31-4*q]; st.y = a[30-4*q]; st.z = a[29-4*q]; st.w = a[28-4*q];
            op[q] = st;
        }
    }
}

// ---------------- mlp: j-split across wave pairs, 64 h regs/lane -------------
// R6 post-mortem: 128 named h scalars -> compiler sank the loads into the
// kt-loop instead of allocating ~150 VGPRs (VGPR stayed 84, 8x L2 re-reads,
// 271 us). Fix: wave 2m holds the 64 FORWARD h for a 64-t tile, wave 2m+1
// the 64 BACKWARD h for the same tile -> ~95 VGPRs/lane (inside the RA's
// comfort zone). w0 bases stay wave-uniform (jh*64) -> s_loads. Partial sums
// combined per k-tile through an 8 KB LDS buffer (lane=t -> conflict-free).
#define REP16(M) M(0) M(1) M(2) M(3) M(4) M(5) M(6) M(7) \
                 M(8) M(9) M(10) M(11) M(12) M(13) M(14) M(15)
#define REP64(M) \
  M(0) M(1) M(2) M(3) M(4) M(5) M(6) M(7) M(8) M(9) M(10) M(11) M(12) M(13) M(14) M(15) \
  M(16) M(17) M(18) M(19) M(20) M(21) M(22) M(23) M(24) M(25) M(26) M(27) M(28) M(29) M(30) M(31) \
  M(32) M(33) M(34) M(35) M(36) M(37) M(38) M(39) M(40) M(41) M(42) M(43) M(44) M(45) M(46) M(47) \
  M(48) M(49) M(50) M(51) M(52) M(53) M(54) M(55) M(56) M(57) M(58) M(59) M(60) M(61) M(62) M(63)

#define WF4(i, OFF, A, B, C, D) { \
    float4 wq = *(const float4*)(wk + (OFF) + (i) * 128); \
    c##i = fmaf(wq.x, A, c##i); c##i = fmaf(wq.y, B, c##i); \
    c##i = fmaf(wq.z, C, c##i); c##i = fmaf(wq.w, D, c##i); }

#define CHUNK(OFF, A, B, C, D) \
    WF4(0,OFF,A,B,C,D)  WF4(1,OFF,A,B,C,D)  WF4(2,OFF,A,B,C,D)  WF4(3,OFF,A,B,C,D)  \
    WF4(4,OFF,A,B,C,D)  WF4(5,OFF,A,B,C,D)  WF4(6,OFF,A,B,C,D)  WF4(7,OFF,A,B,C,D)  \
    WF4(8,OFF,A,B,C,D)  WF4(9,OFF,A,B,C,D)  WF4(10,OFF,A,B,C,D) WF4(11,OFF,A,B,C,D) \
    WF4(12,OFF,A,B,C,D) WF4(13,OFF,A,B,C,D) WF4(14,OFF,A,B,C,D) WF4(15,OFF,A,B,C,D)

__global__ __launch_bounds__(256, 4) void mlp_kernel(
    const float* __restrict__ xh,
    const float* __restrict__ w0, const float* __restrict__ b0,
    const float* __restrict__ w1, const float* __restrict__ b1,
    float* __restrict__ out)
{
    const int lane = threadIdx.x & 63;
    const int wid  = __builtin_amdgcn_readfirstlane(threadIdx.x >> 6); // 0..3
    const int th   = wid >> 1;       // t-tile within block (0/1)
    const int jh   = wid & 1;        // j-half: 0 = forward h, 1 = backward h
    const int blk  = blockIdx.x;     // 0..2047, 128 t each
    const int b    = blk >> 4;       // 16 blocks per batch (TT/128)
    const int t    = ((blk & 15) << 7) + (th << 6) + lane;

    const float* p = xh + (size_t)(jh * BB + b) * HH * TT + t;

    // this wave's 64 h values -> named scalars (one coalesced load each)
    #define LH(j) const float h##j = p[(size_t)(j) * TT];
    REP64(LH)
    #undef LH

    __shared__ float xch[2][16][64];   // [t-tile][k-in-tile][t-lane]

    float oa = 0.0f;

    #pragma unroll 1
    for (int kt = 0; kt < 8; ++kt) {
        const float* wk = w0 + kt * 16 * 128 + jh * 64;   // wave-uniform base

        // even waves seed with b0 (preserves (b0+sum_f)+sum_b order)
        #define DC(i) float c##i = jh ? 0.0f : b0[kt * 16 + i];
        REP16(DC)
        #undef DC

        CHUNK(0,  h0,h1,h2,h3)     CHUNK(4,  h4,h5,h6,h7)
        CHUNK(8,  h8,h9,h10,h11)   CHUNK(12, h12,h13,h14,h15)
        CHUNK(16, h16,h17,h18,h19) CHUNK(20, h20,h21,h22,h23)
        CHUNK(24, h24,h25,h26,h27) CHUNK(28, h28,h29,h30,h31)
        CHUNK(32, h32,h33,h34,h35) CHUNK(36, h36,h37,h38,h39)
        CHUNK(40, h40,h41,h42,h43) CHUNK(44, h44,h45,h46,h47)
        CHUNK(48, h48,h49,h50,h51) CHUNK(52, h52,h53,h54,h55)
        CHUNK(56, h56,h57,h58,h59) CHUNK(60, h60,h61,h62,h63)

        if (jh) {
            #define ST(i) xch[th][i][lane] = c##i;
            REP16(ST)
            #undef ST
        }
        __syncthreads();
        if (!jh) {
            #define EP(i) { float v = c##i + xch[th][i][lane]; \
                            v = fmaxf(v, 0.01f * v); \
                            oa = fmaf(v, w1[kt * 16 + i], oa); }
            REP16(EP)
            #undef EP
        }
        __syncthreads();   // LDS reused next kt
    }

    if (!jh) out[(size_t)b * TT + t] = oa + b1[0];
}

extern "C" void kernel_launch(void* const* d_in, const int* in_sizes, int n_in,
                              void* d_out, int out_size, void* d_ws, size_t ws_size,
                              hipStream_t stream) {
    (void)in_sizes; (void)n_in; (void)out_size; (void)ws_size;
    const float* x    = (const float*)d_in[0];
    const float* Wihf = (const float*)d_in[1];
    const float* Whhf = (const float*)d_in[2];
    const float* bihf = (const float*)d_in[3];
    const float* bhhf = (const float*)d_in[4];
    const float* Wihb = (const float*)d_in[5];
    const float* Whhb = (const float*)d_in[6];
    const float* bihb = (const float*)d_in[7];
    const float* bhhb = (const float*)d_in[8];
    const float* ff0w = (const float*)d_in[9];
    const float* ff0b = (const float*)d_in[10];
    const float* ff1w = (const float*)d_in[11];
    const float* ff1b = (const float*)d_in[12];
    float* xh = (float*)d_ws;

    proj_kernel<<<dim3(BB * (TT / 64)), dim3(256), 0, stream>>>(
        x, Wihf, bihf, bhhf, Wihb, bihb, bhhb, xh);
    rnn_kernel<<<dim3(2 * BB * HH), dim3(64), 0, stream>>>(Whhf, Whhb, xh);
    mlp_kernel<<<dim3(2 * BB * (TT / 128) / 2), dim3(256), 0, stream>>>(
        xh, ff0w, ff0b, ff1w, ff1b, (float*)d_out);
}